// Round 9
// baseline (310.256 us; speedup 1.0000x reference)
//
#include <hip/hip_runtime.h>
#include <hip/hip_bf16.h>

// N=256, T=1024, H=512, M=64, D=64
#define HH 512
#define MM 64
#define DDIM 64
#define TSTEPS 1024
#define NB 16       // samples per chain
#define NPAIR 8     // group pairs (16 groups / 2)
#define NCHUNK 32   // time chunks -> grid = NPAIR*NCHUNK = 256 blocks
#define WARMUP 8    // washout: residual ~18*(0.9*E[sech^2])^8 ~ 1e-3 << quant noise
#define OUTS 32     // outputs per chunk

#define XSTR 528    // xq row stride BYTES (16*33)
#define USTR 72     // xib row stride SHORTS (144B)

using bf16x8 = __attribute__((ext_vector_type(8))) short;
using i32x4  = __attribute__((ext_vector_type(4))) int;
using f32x4  = __attribute__((ext_vector_type(4))) float;

#define TWO_LOG2E 2.8853901817f
#define C1_AX 4.4374178e-5f   // 2log2e/(512*127)
#define C3_WX 3.0757400e-5f   // 1/(256*127)

__device__ __align__(16) unsigned char g_Ai8[HH * HH];
__device__ __align__(16) unsigned char g_Wi8[DDIM * HH];
__device__ __align__(16) unsigned short g_C[HH * MM];   // bf16 [h][m], pre-scaled

__device__ __forceinline__ unsigned short f2bf(float f) {
    unsigned u = __builtin_bit_cast(unsigned, f);
    unsigned r = (u + 0x7FFFu + ((u >> 16) & 1u)) >> 16;  // RNE
    return (unsigned short)r;
}

__device__ __forceinline__ unsigned char q8(float v, float s) {
    float r = rintf(v * s);
    r = fminf(fmaxf(r, -127.f), 127.f);
    return (unsigned char)(signed char)(int)r;
}

__global__ void prep_kernel(const float* __restrict__ A, const float* __restrict__ C,
                            const float* __restrict__ W) {
    int i = blockIdx.x * 256 + threadIdx.x;
    if (i < HH * HH) {      // A -> i8 frag-packed
        int seg = i >> 10, r = i & 1023;
        int tg = seg >> 3, kt = seg & 7;
        int lane = r >> 4, e = r & 15;
        int ln = lane & 15, lk = lane >> 4;
        g_Ai8[i] = q8(A[(tg * 16 + ln) * HH + kt * 64 + lk * 16 + e], 512.f);
    }
    if (i < DDIM * HH) {    // W -> i8 frag-packed
        int seg = i >> 10, r = i & 1023;
        int dt = seg >> 3, kt = seg & 7;
        int lane = r >> 4, e = r & 15;
        int ln = lane & 15, lk = lane >> 4;
        g_Wi8[i] = q8(W[(dt * 16 + ln) * HH + kt * 64 + lk * 16 + e], 256.f);
    }
    if (i < HH * MM) g_C[i] = f2bf(C[i] * TWO_LOG2E);
}

// 256 blocks x 512 threads (8 waves). TWO independent recurrence chains per
// block (two sample groups, same time window) sharing the register-resident A.
// One barrier advances both chains one step. Waves 0-3 own chain0's B/eta/out/
// xi-prefetch; waves 4-7 own chain1's. All waves do phase A for both chains.
__attribute__((amdgpu_waves_per_eu(2, 2)))
__global__ void __launch_bounds__(512, 2)
esn_kernel(const float* __restrict__ xi, const float* __restrict__ eta,
           float* __restrict__ out) {
    __shared__ __align__(16) unsigned char  xq0[2][16 * XSTR];  // chain0 i8 state dbuf
    __shared__ __align__(16) unsigned char  xq1[2][16 * XSTR];  // chain1
    __shared__ __align__(16) unsigned short xib0[2][16 * USTR]; // chain0 xi dbuf
    __shared__ __align__(16) unsigned short xib1[2][16 * USTR]; // chain1
    __shared__ __align__(16) unsigned char  Wl[DDIM * HH];      // i8 W frags

    const int tid = threadIdx.x, lane = tid & 63, w = tid >> 6;
    const int ln = lane & 15, lk = lane >> 4;
    const int gp = blockIdx.x & (NPAIR - 1), c = (int)blockIdx.x >> 3;
    const bool ch0 = (w < 4);                       // this wave's service chain
    const int n0c = gp * 32 + (ch0 ? 0 : 16);       // its sample base
    const int out_start = OUTS * c;
    const int t0 = (c == 0) ? 0 : out_start - WARMUP;
    const int zgate = out_start + 1;
    const int out_end = out_start + OUTS;

    // ---- prologue ----
    for (int i4 = tid; i4 < DDIM * HH / 16; i4 += 512)
        ((i32x4*)Wl)[i4] = ((const i32x4*)g_Wi8)[i4];
    i32x4 af[4][8];                                  // shared A: 128 regs
#pragma unroll
    for (int tl = 0; tl < 4; ++tl)
#pragma unroll
        for (int kt = 0; kt < 8; ++kt)
            af[tl][kt] = *reinterpret_cast<const i32x4*>(
                &g_Ai8[(((w * 4 + tl) * 8 + kt) << 10) + lane * 16]);
    bf16x8 cfr[4][2];
#pragma unroll
    for (int tl = 0; tl < 4; ++tl)
#pragma unroll
        for (int kc = 0; kc < 2; ++kc)
            cfr[tl][kc] = *reinterpret_cast<const bf16x8*>(
                &g_C[(w * 64 + tl * 16 + ln) * MM + kc * 32 + lk * 8]);

    const int jn = (tid & 255) >> 4, jm = (tid & 15) * 4;
    {   // xi_{t0} -> xib[0], own chain (256 threads each)
        f32x4 v = __builtin_nontemporal_load(reinterpret_cast<const f32x4*>(
            &xi[((long)(n0c + jn) * TSTEPS + t0) * MM + jm]));
        unsigned lo, hi;
        asm("v_cvt_pk_bf16_f32 %0, %1, %2" : "=v"(lo) : "v"(v[0]), "v"(v[1]));
        asm("v_cvt_pk_bf16_f32 %0, %1, %2" : "=v"(hi) : "v"(v[2]), "v"(v[3]));
        uint2 pk2; pk2.x = lo; pk2.y = hi;
        if (ch0) *reinterpret_cast<uint2*>(&xib0[0][jn * USTR + jm]) = pk2;
        else     *reinterpret_cast<uint2*>(&xib1[0][jn * USTR + jm]) = pk2;
    }
    __syncthreads();

    const int rb = ln * XSTR + lk * 16;            // xq read base (bytes)
    const int wb = ln * XSTR + w * 64 + lk * 4;    // xq write base (bytes)
    const int ub = ln * USTR + lk * 8;             // xib read base (shorts)
    const int sb = jn * USTR + jm;                 // xib stash base (shorts)

    bf16x8 bu00 = *reinterpret_cast<const bf16x8*>(&xib0[0][ub]);
    bf16x8 bu01 = *reinterpret_cast<const bf16x8*>(&xib0[0][ub + 32]);
    bf16x8 bu10 = *reinterpret_cast<const bf16x8*>(&xib1[0][ub]);
    bf16x8 bu11 = *reinterpret_cast<const bf16x8*>(&xib1[0][ub + 32]);
    i32x4 xf0[8], xf1[8];
#pragma unroll
    for (int kt = 0; kt < 8; ++kt) { xf0[kt] = i32x4{0,0,0,0}; xf1[kt] = i32x4{0,0,0,0}; }

    // streaming pointers (own chain); eta/out track (t-1)
    const float* xi_pf = xi + ((long)(n0c + jn) * TSTEPS + (t0 + 1)) * MM + jm;
    const float* eta_p = eta + ((long)(n0c + ln) * TSTEPS + (t0 - 1)) * DDIM + (w & 3) * 16 + lk * 4;
    float*       out_p = out + ((long)(n0c + ln) * TSTEPS + (t0 - 1)) * DDIM + (w & 3) * 16 + lk * 4;

    int p = 0;
    for (int t = t0; t < out_end; ++t) {
        const int q = p ^ 1;

        // early VMEM issue (own chain)
        f32x4 ev;
        const bool wo = (t >= zgate);
        if (wo) ev = __builtin_nontemporal_load(reinterpret_cast<const f32x4*>(eta_p));
        f32x4 xiv;
        const bool pf = (t + 1 < out_end);
        if (pf) xiv = __builtin_nontemporal_load(reinterpret_cast<const f32x4*>(xi_pf));

        // ---- hoisted phase B: Z_{t-1} = W x_{t-1}, own chain ----
        i32x4 iz = {0, 0, 0, 0};
        if (wo) {
            if (ch0) {
#pragma unroll
                for (int kt = 0; kt < 8; ++kt) {
                    i32x4 wf = *reinterpret_cast<const i32x4*>(
                        &Wl[(((w & 3) * 8 + kt) << 10) + lane * 16]);
                    iz = __builtin_amdgcn_mfma_i32_16x16x64_i8(wf, xf0[kt], iz, 0, 0, 0);
                }
            } else {
#pragma unroll
                for (int kt = 0; kt < 8; ++kt) {
                    i32x4 wf = *reinterpret_cast<const i32x4*>(
                        &Wl[(((w & 3) * 8 + kt) << 10) + lane * 16]);
                    iz = __builtin_amdgcn_mfma_i32_16x16x64_i8(wf, xf1[kt], iz, 0, 0, 0);
                }
            }
        }

        // ---- phase A, both chains, tiles interleaved for ILP ----
        unsigned char* xw0 = &xq0[q][0];
        unsigned char* xw1 = &xq1[q][0];
#pragma unroll
        for (int tl = 0; tl < 4; ++tl) {
            // chain 0 tile
            f32x4 ua0 = {0.f, 0.f, 0.f, 0.f};
            ua0 = __builtin_amdgcn_mfma_f32_16x16x32_bf16(cfr[tl][0], bu00, ua0, 0, 0, 0);
            ua0 = __builtin_amdgcn_mfma_f32_16x16x32_bf16(cfr[tl][1], bu01, ua0, 0, 0, 0);
            i32x4 ia0 = {0, 0, 0, 0};
#pragma unroll
            for (int kt = 0; kt < 8; ++kt)
                ia0 = __builtin_amdgcn_mfma_i32_16x16x64_i8(af[tl][kt], xf0[kt], ia0, 0, 0, 0);
            // chain 1 tile (independent DAG — overlaps chain0's tanh below)
            f32x4 ua1 = {0.f, 0.f, 0.f, 0.f};
            ua1 = __builtin_amdgcn_mfma_f32_16x16x32_bf16(cfr[tl][0], bu10, ua1, 0, 0, 0);
            ua1 = __builtin_amdgcn_mfma_f32_16x16x32_bf16(cfr[tl][1], bu11, ua1, 0, 0, 0);
            i32x4 ia1 = {0, 0, 0, 0};
#pragma unroll
            for (int kt = 0; kt < 8; ++kt)
                ia1 = __builtin_amdgcn_mfma_i32_16x16x64_i8(af[tl][kt], xf1[kt], ia1, 0, 0, 0);
            {   // chain0 tanh + pack + write
                unsigned b[4];
#pragma unroll
                for (int j2 = 0; j2 < 4; ++j2) {
                    float s2 = fmaf((float)ia0[j2], C1_AX, ua0[j2]);
                    float e = exp2f(s2);
                    float r = __builtin_amdgcn_rcpf(e + 1.0f);
                    float v = fmaf(r, -254.0f, 12583039.0f);
                    b[j2] = __builtin_bit_cast(unsigned, v);
                }
                unsigned p01 = __builtin_amdgcn_perm(b[1], b[0], 0x00000400u);
                unsigned p23 = __builtin_amdgcn_perm(b[3], b[2], 0x00000400u);
                *reinterpret_cast<unsigned*>(xw0 + wb + tl * 16) =
                    __builtin_amdgcn_perm(p23, p01, 0x05040100u);
            }
            {   // chain1 tanh + pack + write
                unsigned b[4];
#pragma unroll
                for (int j2 = 0; j2 < 4; ++j2) {
                    float s2 = fmaf((float)ia1[j2], C1_AX, ua1[j2]);
                    float e = exp2f(s2);
                    float r = __builtin_amdgcn_rcpf(e + 1.0f);
                    float v = fmaf(r, -254.0f, 12583039.0f);
                    b[j2] = __builtin_bit_cast(unsigned, v);
                }
                unsigned p01 = __builtin_amdgcn_perm(b[1], b[0], 0x00000400u);
                unsigned p23 = __builtin_amdgcn_perm(b[3], b[2], 0x00000400u);
                *reinterpret_cast<unsigned*>(xw1 + wb + tl * 16) =
                    __builtin_amdgcn_perm(p23, p01, 0x05040100u);
            }
        }

        // Z epilogue + store (own chain)
        if (wo) {
            f32x4 z;
#pragma unroll
            for (int j2 = 0; j2 < 4; ++j2)
                z[j2] = fmaf((float)iz[j2], C3_WX, ev[j2]);
            __builtin_nontemporal_store(z, reinterpret_cast<f32x4*>(out_p));
        }
        if (pf) {   // stash xi_{t+1}, own chain
            unsigned lo, hi;
            asm("v_cvt_pk_bf16_f32 %0, %1, %2" : "=v"(lo) : "v"(xiv[0]), "v"(xiv[1]));
            asm("v_cvt_pk_bf16_f32 %0, %1, %2" : "=v"(hi) : "v"(xiv[2]), "v"(xiv[3]));
            uint2 pk2; pk2.x = lo; pk2.y = hi;
            if (ch0) *reinterpret_cast<uint2*>(&xib0[q][sb]) = pk2;
            else     *reinterpret_cast<uint2*>(&xib1[q][sb]) = pk2;
        }
        __syncthreads();   // x_t and xi_{t+1} visible (both chains)

        // ---- reload hoisted frags for next iteration ----
        const unsigned char* xr0 = &xq0[q][rb];
        const unsigned char* xr1 = &xq1[q][rb];
#pragma unroll
        for (int kt = 0; kt < 8; ++kt) {
            xf0[kt] = *reinterpret_cast<const i32x4*>(xr0 + kt * 64);
            xf1[kt] = *reinterpret_cast<const i32x4*>(xr1 + kt * 64);
        }
        bu00 = *reinterpret_cast<const bf16x8*>(&xib0[q][ub]);
        bu01 = *reinterpret_cast<const bf16x8*>(&xib0[q][ub + 32]);
        bu10 = *reinterpret_cast<const bf16x8*>(&xib1[q][ub]);
        bu11 = *reinterpret_cast<const bf16x8*>(&xib1[q][ub + 32]);

        xi_pf += MM; eta_p += DDIM; out_p += DDIM;
        p = q;
    }

    // ---- flush: Z_{out_end-1}, own chain ----
    {
        f32x4 ev = __builtin_nontemporal_load(reinterpret_cast<const f32x4*>(eta_p));
        i32x4 iz = {0, 0, 0, 0};
        if (ch0) {
#pragma unroll
            for (int kt = 0; kt < 8; ++kt) {
                i32x4 wf = *reinterpret_cast<const i32x4*>(
                    &Wl[(((w & 3) * 8 + kt) << 10) + lane * 16]);
                iz = __builtin_amdgcn_mfma_i32_16x16x64_i8(wf, xf0[kt], iz, 0, 0, 0);
            }
        } else {
#pragma unroll
            for (int kt = 0; kt < 8; ++kt) {
                i32x4 wf = *reinterpret_cast<const i32x4*>(
                    &Wl[(((w & 3) * 8 + kt) << 10) + lane * 16]);
                iz = __builtin_amdgcn_mfma_i32_16x16x64_i8(wf, xf1[kt], iz, 0, 0, 0);
            }
        }
        f32x4 z;
#pragma unroll
        for (int j2 = 0; j2 < 4; ++j2)
            z[j2] = fmaf((float)iz[j2], C3_WX, ev[j2]);
        __builtin_nontemporal_store(z, reinterpret_cast<f32x4*>(out_p));
    }
}

extern "C" void kernel_launch(void* const* d_in, const int* in_sizes, int n_in,
                              void* d_out, int out_size, void* d_ws, size_t ws_size,
                              hipStream_t stream) {
    const float* A   = (const float*)d_in[0];
    const float* C   = (const float*)d_in[1];
    const float* W   = (const float*)d_in[2];
    const float* xi  = (const float*)d_in[3];
    const float* eta = (const float*)d_in[4];
    float* out = (float*)d_out;

    hipLaunchKernelGGL(prep_kernel, dim3((HH * HH + 255) / 256), dim3(256), 0, stream, A, C, W);
    hipLaunchKernelGGL(esn_kernel, dim3(NPAIR * NCHUNK), dim3(512), 0, stream, xi, eta, out);
}

// Round 10
// 126.731 us; speedup vs baseline: 2.4482x; 2.4482x over previous
//
#include <hip/hip_runtime.h>
#include <hip/hip_bf16.h>

// N=256, T=1024, H=512, M=64, D=64
#define HH 512
#define MM 64
#define DDIM 64
#define TSTEPS 1024
#define NB 16       // samples per block
#define NGRP 16     // sample groups
#define NCHUNK 16   // time chunks -> grid = 256 blocks
#define WARMUP 6    // washout: residual ~21*(0.35)^6 ~ 0.04 (L2) -> dZ ~ 4e-3 << quant noise
// chunk c: outputs [64c, 64(c+1)); t0 = max(0, 64c-6)

#define XSTR 528    // xq row stride BYTES (16*33)
#define USTR 72     // xib row stride SHORTS (144B)

using bf16x8 = __attribute__((ext_vector_type(8))) short;
using i32x4  = __attribute__((ext_vector_type(4))) int;
using f32x4  = __attribute__((ext_vector_type(4))) float;

// Quant scales: A*512, W*256, x*127. C and the A-descale carry 2*log2(e) so the
// tanh argument arrives pre-scaled for exp2.
#define TWO_LOG2E 2.8853901817f
#define C1_AX 4.4374178e-5f   // 2log2e/(512*127)
#define C3_WX 3.0757400e-5f   // 1/(256*127)

__device__ __align__(16) unsigned char g_Ai8[HH * HH];
__device__ __align__(16) unsigned char g_Wi8[DDIM * HH];
__device__ __align__(16) unsigned short g_C[HH * MM];   // bf16 [h][m], pre-scaled

__device__ __forceinline__ unsigned short f2bf(float f) {
    unsigned u = __builtin_bit_cast(unsigned, f);
    unsigned r = (u + 0x7FFFu + ((u >> 16) & 1u)) >> 16;  // RNE
    return (unsigned short)r;
}

__device__ __forceinline__ unsigned char q8(float v, float s) {
    float r = rintf(v * s);
    r = fminf(fmaxf(r, -127.f), 127.f);
    return (unsigned char)(signed char)(int)r;
}

__global__ void prep_kernel(const float* __restrict__ A, const float* __restrict__ C,
                            const float* __restrict__ W) {
    int i = blockIdx.x * 256 + threadIdx.x;
    if (i < HH * HH) {      // A -> i8 frag-packed
        int seg = i >> 10, r = i & 1023;
        int tg = seg >> 3, kt = seg & 7;
        int lane = r >> 4, e = r & 15;
        int ln = lane & 15, lk = lane >> 4;
        g_Ai8[i] = q8(A[(tg * 16 + ln) * HH + kt * 64 + lk * 16 + e], 512.f);
    }
    if (i < DDIM * HH) {    // W -> i8 frag-packed
        int seg = i >> 10, r = i & 1023;
        int dt = seg >> 3, kt = seg & 7;
        int lane = r >> 4, e = r & 15;
        int ln = lane & 15, lk = lane >> 4;
        g_Wi8[i] = q8(W[(dt * 16 + ln) * HH + kt * 64 + lk * 16 + e], 256.f);
    }
    if (i < HH * MM) g_C[i] = f2bf(C[i] * TWO_LOG2E);   // fold 2log2e into C
}

// 256 blocks x 512 threads (8 waves). A resident in regs (128/wave i8); zero
// VMEM in the recurrence; one barrier per step. Iteration t computes
// Z_{t-1} = W x_{t-1} + eta (hoisted) and x_t = tanh(A x_{t-1} + C xi_t).
__attribute__((amdgpu_waves_per_eu(2, 2)))
__global__ void __launch_bounds__(512, 2)
esn_kernel(const float* __restrict__ xi, const float* __restrict__ eta,
           float* __restrict__ out) {
    __shared__ __align__(16) unsigned char  xq[2][16 * XSTR];   // i8 state dbuf
    __shared__ __align__(16) unsigned short xib[2][16 * USTR];  // bf16 xi dbuf
    __shared__ __align__(16) unsigned char  Wl[DDIM * HH];      // i8 W frags

    const int tid = threadIdx.x, lane = tid & 63, w = tid >> 6;
    const int ln = lane & 15, lk = lane >> 4;
    const int g = blockIdx.x & (NGRP - 1), c = (int)blockIdx.x >> 4;
    const int n0 = g * NB;
    const int out_start = 64 * c;                    // first output step
    const int t0 = (c == 0) ? 0 : out_start - WARMUP;
    const int zgate = out_start + 1;                 // first iter that emits Z_{t-1}
    const int out_end = 64 * (c + 1);

    // ---- prologue ----
    for (int i4 = tid; i4 < DDIM * HH / 16; i4 += 512)
        ((i32x4*)Wl)[i4] = ((const i32x4*)g_Wi8)[i4];
    i32x4 af[4][8];                                  // A resident: 128 regs
#pragma unroll
    for (int tl = 0; tl < 4; ++tl)
#pragma unroll
        for (int kt = 0; kt < 8; ++kt)
            af[tl][kt] = *reinterpret_cast<const i32x4*>(
                &g_Ai8[(((w * 4 + tl) * 8 + kt) << 10) + lane * 16]);
    bf16x8 cfr[4][2];
#pragma unroll
    for (int tl = 0; tl < 4; ++tl)
#pragma unroll
        for (int kc = 0; kc < 2; ++kc)
            cfr[tl][kc] = *reinterpret_cast<const bf16x8*>(
                &g_C[(w * 64 + tl * 16 + ln) * MM + kc * 32 + lk * 8]);

    const int jn = (tid & 255) >> 4, jm = (tid & 15) * 4;
    if (tid < 256) {   // xi_{t0} -> xib[0]
        f32x4 v = __builtin_nontemporal_load(reinterpret_cast<const f32x4*>(
            &xi[((long)(n0 + jn) * TSTEPS + t0) * MM + jm]));
        unsigned lo, hi;
        asm("v_cvt_pk_bf16_f32 %0, %1, %2" : "=v"(lo) : "v"(v[0]), "v"(v[1]));
        asm("v_cvt_pk_bf16_f32 %0, %1, %2" : "=v"(hi) : "v"(v[2]), "v"(v[3]));
        uint2 pk2; pk2.x = lo; pk2.y = hi;
        *reinterpret_cast<uint2*>(&xib[0][jn * USTR + jm]) = pk2;
    }
    __syncthreads();

    const int rb = ln * XSTR + lk * 16;            // xq read base (bytes)
    const int wb = ln * XSTR + w * 64 + lk * 4;    // xq write base (bytes)
    const int ub = ln * USTR + lk * 8;             // xib read base (shorts)
    const int sb = jn * USTR + jm;                 // xib stash base (shorts)

    bf16x8 bu0 = *reinterpret_cast<const bf16x8*>(&xib[0][ub]);
    bf16x8 bu1 = *reinterpret_cast<const bf16x8*>(&xib[0][ub + 32]);
    i32x4 xf[8];
#pragma unroll
    for (int kt = 0; kt < 8; ++kt) xf[kt] = i32x4{0, 0, 0, 0};

    // streaming pointers; eta/out track (t-1)
    const float* xi_pf = xi + ((long)(n0 + jn) * TSTEPS + (t0 + 1)) * MM + jm;
    const float* eta_p = eta + ((long)(n0 + ln) * TSTEPS + (t0 - 1)) * DDIM + w * 16 + lk * 4;
    float*       out_p = out + ((long)(n0 + ln) * TSTEPS + (t0 - 1)) * DDIM + w * 16 + lk * 4;

    int p = 0;
    for (int t = t0; t < out_end; ++t) {
        const int q = p ^ 1;

        // early VMEM issue
        f32x4 ev;
        const bool wo = (w < 4) && (t >= zgate);
        if (wo) ev = __builtin_nontemporal_load(reinterpret_cast<const f32x4*>(eta_p));
        f32x4 xiv;
        const bool pf = (w >= 4) && (t + 1 < out_end);
        if (pf) xiv = __builtin_nontemporal_load(reinterpret_cast<const f32x4*>(xi_pf));

        // ---- hoisted phase B: Z_{t-1} = W x_{t-1} (same xf as phase A below) ----
        i32x4 iz = {0, 0, 0, 0};
        if (wo) {
#pragma unroll
            for (int kt = 0; kt < 8; ++kt) {
                i32x4 wf = *reinterpret_cast<const i32x4*>(&Wl[((w * 8 + kt) << 10) + lane * 16]);
                iz = __builtin_amdgcn_mfma_i32_16x16x64_i8(wf, xf[kt], iz, 0, 0, 0);
            }
        }

        // ---- phase A: s2 = 2log2e*(A x_{t-1} + C xi_t), x_t = tanh via exp2 ----
        // T5: role-split waves (w<4: B+Z; w>=4: prefetch) -> setprio arbitrates.
        __builtin_amdgcn_s_setprio(1);
        unsigned char* xwq = &xq[q][0];
#pragma unroll
        for (int tl = 0; tl < 4; ++tl) {
            f32x4 uacc = {0.f, 0.f, 0.f, 0.f};
            uacc = __builtin_amdgcn_mfma_f32_16x16x32_bf16(cfr[tl][0], bu0, uacc, 0, 0, 0);
            uacc = __builtin_amdgcn_mfma_f32_16x16x32_bf16(cfr[tl][1], bu1, uacc, 0, 0, 0);
            i32x4 ia = {0, 0, 0, 0};
#pragma unroll
            for (int kt = 0; kt < 8; ++kt)
                ia = __builtin_amdgcn_mfma_i32_16x16x64_i8(af[tl][kt], xf[kt], ia, 0, 0, 0);
            unsigned b[4];
#pragma unroll
            for (int j2 = 0; j2 < 4; ++j2) {  // 3 VALU + 2 trans per element
                float fia = (float)ia[j2];
                float s2 = fmaf(fia, C1_AX, uacc[j2]);   // already x 2log2e
                float e = exp2f(s2);                     // native v_exp_f32
                float r = __builtin_amdgcn_rcpf(e + 1.0f);
                float v = fmaf(r, -254.0f, 12583039.0f); // low byte = i8(127*tanh)
                b[j2] = __builtin_bit_cast(unsigned, v);
            }
            unsigned p01 = __builtin_amdgcn_perm(b[1], b[0], 0x00000400u);
            unsigned p23 = __builtin_amdgcn_perm(b[3], b[2], 0x00000400u);
            unsigned pk  = __builtin_amdgcn_perm(p23, p01, 0x05040100u);
            *reinterpret_cast<unsigned*>(xwq + wb + tl * 16) = pk;
        }
        __builtin_amdgcn_s_setprio(0);

        // deferred Z epilogue + store
        if (wo) {
            f32x4 z;
#pragma unroll
            for (int j2 = 0; j2 < 4; ++j2)
                z[j2] = fmaf((float)iz[j2], C3_WX, ev[j2]);
            __builtin_nontemporal_store(z, reinterpret_cast<f32x4*>(out_p));
        }
        if (pf) {   // stash xi_{t+1} as bf16
            unsigned lo, hi;
            asm("v_cvt_pk_bf16_f32 %0, %1, %2" : "=v"(lo) : "v"(xiv[0]), "v"(xiv[1]));
            asm("v_cvt_pk_bf16_f32 %0, %1, %2" : "=v"(hi) : "v"(xiv[2]), "v"(xiv[3]));
            uint2 pk2; pk2.x = lo; pk2.y = hi;
            *reinterpret_cast<uint2*>(&xib[q][sb]) = pk2;
        }
        __syncthreads();   // x_t and xi_{t+1} visible

        // ---- reload hoisted frags for next iteration (and final flush) ----
        const unsigned char* xrq = &xq[q][rb];
#pragma unroll
        for (int kt = 0; kt < 8; ++kt)
            xf[kt] = *reinterpret_cast<const i32x4*>(xrq + kt * 64);
        bu0 = *reinterpret_cast<const bf16x8*>(&xib[q][ub]);
        bu1 = *reinterpret_cast<const bf16x8*>(&xib[q][ub + 32]);

        xi_pf += MM; eta_p += DDIM; out_p += DDIM;
        p = q;
    }

    // ---- flush: Z_{out_end-1} = W x_{out_end-1} + eta ----
    if (w < 4) {
        f32x4 ev = __builtin_nontemporal_load(reinterpret_cast<const f32x4*>(eta_p));
        i32x4 iz = {0, 0, 0, 0};
#pragma unroll
        for (int kt = 0; kt < 8; ++kt) {
            i32x4 wf = *reinterpret_cast<const i32x4*>(&Wl[((w * 8 + kt) << 10) + lane * 16]);
            iz = __builtin_amdgcn_mfma_i32_16x16x64_i8(wf, xf[kt], iz, 0, 0, 0);
        }
        f32x4 z;
#pragma unroll
        for (int j2 = 0; j2 < 4; ++j2)
            z[j2] = fmaf((float)iz[j2], C3_WX, ev[j2]);
        __builtin_nontemporal_store(z, reinterpret_cast<f32x4*>(out_p));
    }
}

extern "C" void kernel_launch(void* const* d_in, const int* in_sizes, int n_in,
                              void* d_out, int out_size, void* d_ws, size_t ws_size,
                              hipStream_t stream) {
    const float* A   = (const float*)d_in[0];
    const float* C   = (const float*)d_in[1];
    const float* W   = (const float*)d_in[2];
    const float* xi  = (const float*)d_in[3];
    const float* eta = (const float*)d_in[4];
    float* out = (float*)d_out;

    hipLaunchKernelGGL(prep_kernel, dim3((HH * HH + 255) / 256), dim3(256), 0, stream, A, C, W);
    hipLaunchKernelGGL(esn_kernel, dim3(NCHUNK * NGRP), dim3(512), 0, stream, xi, eta, out);
}